// Round 5
// baseline (231.075 us; speedup 1.0000x reference)
//
#include <hip/hip_runtime.h>

// Sparse 3D conv (K=3, stride=2, pad=1), dense output, rulebook + gather.
// Inputs: features [N,32] f32, W [3,3,3,32,64] f32, coors [N,4] i32 (b,z,y,x).
// Output: [B,64,64,64,64] f32 flat. Exactly-once writes, no output memset.
// ws: [ hist nT | prefix nT+1 | cursor nT | pad | pairs N*8 | W_bf16 27*64*32 ]

#define CIN   32
#define COUT  64
#define OUTD  64
#define TILE  4
#define NTILE 16          // OUTD/TILE
#define CAP2  512         // LDS pair-list chunk
#define NPTS  128

// Valid (k, o) options along one axis: o = (p+1-k)/2, parity-matched, 0<=o<64.
__device__ __forceinline__ int axis_opts(int p, int* k, int* o) {
    int cnt = 0;
    const int kp = (p + 1) & 1;          // smallest parity-matching k
    const int o0 = (p + 1 - kp) >> 1;    // >= 0 always
    if (o0 < OUTD) { k[cnt] = kp; o[cnt] = o0; ++cnt; }
    if (kp == 0) {                       // k=2 shares parity with k=0
        const int o1 = o0 - 1;
        if (o1 >= 0) { k[cnt] = 2; o[cnt] = o1; ++cnt; }
    }
    return cnt;
}

// ---------- rulebook pass 1: per-tile pair counts ----------
__global__ void rulebook_count(const int4* __restrict__ coors,
                               int* __restrict__ hist, int N)
{
    const int i = blockIdx.x * 256 + threadIdx.x;
    if (i >= N) return;
    const int4 c = coors[i];             // (b, z, y, x)
    int kz[2], oz[2], ky[2], oy[2], kx[2], ox[2];
    const int nz = axis_opts(c.y, kz, oz);
    const int ny = axis_opts(c.z, ky, oy);
    const int nx = axis_opts(c.w, kx, ox);
    for (int az = 0; az < nz; ++az)
        for (int ay = 0; ay < ny; ++ay)
            for (int ax = 0; ax < nx; ++ax) {
                const int tile = ((c.x * NTILE + (oz[az] >> 2)) * NTILE +
                                  (oy[ay] >> 2)) * NTILE + (ox[ax] >> 2);
                atomicAdd(&hist[tile], 1);
            }
}

// ---------- rulebook pass 2: prefix scan over nT tiles (one block) ----------
__global__ void prefix_scan(const int* __restrict__ hist, int* __restrict__ prefix,
                            int* __restrict__ cursor, int nT)
{
    __shared__ int part[256];
    const int t = threadIdx.x;
    const int chunk = nT >> 8;           // nT is a multiple of 256
    int s = 0;
    for (int i = 0; i < chunk; ++i) s += hist[t * chunk + i];
    part[t] = s;
    __syncthreads();
    if (t == 0) { int r = 0; for (int i = 0; i < 256; ++i) { int v = part[i]; part[i] = r; r += v; } }
    __syncthreads();
    int run = part[t];
    for (int i = 0; i < chunk; ++i) {
        const int idx = t * chunk + i;
        prefix[idx] = run; cursor[idx] = run; run += hist[idx];
    }
    if (t == 255) prefix[nT] = run;
}

// ---------- rulebook pass 3: scatter packed pairs sorted by tile ----------
__global__ void rulebook_fill(const int4* __restrict__ coors,
                              int* __restrict__ cursor, int* __restrict__ pairs, int N)
{
    const int i = blockIdx.x * 256 + threadIdx.x;
    if (i >= N) return;
    const int4 c = coors[i];
    int kz[2], oz[2], ky[2], oy[2], kx[2], ox[2];
    const int nz = axis_opts(c.y, kz, oz);
    const int ny = axis_opts(c.z, ky, oy);
    const int nx = axis_opts(c.w, kx, ox);
    for (int az = 0; az < nz; ++az)
        for (int ay = 0; ay < ny; ++ay)
            for (int ax = 0; ax < nx; ++ax) {
                const int tile = ((c.x * NTILE + (oz[az] >> 2)) * NTILE +
                                  (oy[ay] >> 2)) * NTILE + (ox[ax] >> 2);
                const int kidx = (kz[az] * 3 + ky[ay]) * 3 + kx[ax];
                const int vox  = ((oz[az] & 3) * TILE + (oy[ay] & 3)) * TILE + (ox[ax] & 3);
                const int pos  = atomicAdd(&cursor[tile], 1);
                pairs[pos] = (i << 11) | (kidx << 6) | vox;
            }
}

// ---------- W transpose+quantize: [27][32][64] f32 -> [27][64][32] bf16 ----------
__global__ void conv_w_bf16(const float* __restrict__ W, ushort* __restrict__ wsW)
{
    const int k = blockIdx.x;            // 27 blocks
    for (int i = threadIdx.x; i < CIN * COUT; i += 256) {
        const int c = i >> 6, ch = i & 63;
        const unsigned u = __float_as_uint(W[k * CIN * COUT + i]);
        const unsigned r = (u + 0x7fffu + ((u >> 16) & 1u)) >> 16;   // RNE
        wsW[(k << 11) + (ch << 5) + c] = (ushort)r;
    }
}

// ---------- gather: one block per 4x4x4 output tile, no search ----------
__global__ __launch_bounds__(256) void gather_tile(
    const float* __restrict__ feats, const ushort* __restrict__ wsW,
    const int* __restrict__ pairs, const int* __restrict__ prefix,
    float* __restrict__ out)
{
    __shared__ float acc[TILE * TILE * TILE * COUT];   // 16 KB
    __shared__ int   list[CAP2];                        // 2 KB

    const int tid = threadIdx.x;
    const int bid = blockIdx.x;
    int t = bid;
    const int ox0 = (t & 15) * TILE; t >>= 4;
    const int oy0 = (t & 15) * TILE; t >>= 4;
    const int oz0 = (t & 15) * TILE; t >>= 4;
    const int b   = t;

    for (int i = tid; i < TILE * TILE * TILE * COUT; i += 256) acc[i] = 0.f;

    const int start = prefix[bid], end = prefix[bid + 1];
    const int wv = tid >> 6, ch = tid & 63;

    for (int base = start; base < end; base += CAP2) {
        const int m = min(CAP2, end - base);
        __syncthreads();
        for (int i = tid; i < m; i += 256) list[i] = pairs[base + i];
        __syncthreads();

        #pragma unroll 2
        for (int i = wv; i < m; i += 4) {
            const int e = list[i];
            const int vox = e & 63, k = (e >> 6) & 31, j = e >> 11;
            const float4* fp = (const float4*)(feats + (size_t)j * CIN);
            const uint4*  wp = (const uint4*)(wsW + (k << 11) + (ch << 5));
            float4 f[8];
            #pragma unroll
            for (int q = 0; q < 8; ++q) f[q] = fp[q];
            float s = 0.f;
            #pragma unroll
            for (int q = 0; q < 4; ++q) {
                const uint4 wq = wp[q];
                const float4 fa = f[2 * q], fb = f[2 * q + 1];
                s += fa.x * __uint_as_float(wq.x << 16);
                s += fa.y * __uint_as_float(wq.x & 0xffff0000u);
                s += fa.z * __uint_as_float(wq.y << 16);
                s += fa.w * __uint_as_float(wq.y & 0xffff0000u);
                s += fb.x * __uint_as_float(wq.z << 16);
                s += fb.y * __uint_as_float(wq.z & 0xffff0000u);
                s += fb.z * __uint_as_float(wq.w << 16);
                s += fb.w * __uint_as_float(wq.w & 0xffff0000u);
            }
            atomicAdd(&acc[vox * COUT + ch], s);        // ds_add_f32, conflict-free
        }
    }
    __syncthreads();

    // Write tile: 16 rows of TILE*COUT=256 contiguous floats, float4-coalesced.
    #pragma unroll
    for (int it = 0; it < 4; ++it) {
        const int i = (it * 256 + tid) * 4;
        const int row = i >> 8;
        const int vz = row >> 2, vy = row & 3;
        const int inrow = i & 255;
        const size_t g = ((((size_t)b * OUTD + (oz0 + vz)) * OUTD + (oy0 + vy)) * OUTD + ox0) * COUT + inrow;
        *(float4*)(out + g) = *(const float4*)(acc + i);
    }
}

// ---------- fallback (ws too small): round-1 scatter ----------
__global__ __launch_bounds__(256, 4) void spconv_scatter(
    const float* __restrict__ feats, const float* __restrict__ Wt,
    const int* __restrict__ coors, float* __restrict__ out, int N)
{
    __shared__ float sf[NPTS][CIN];
    __shared__ int   sc[NPTS][4];
    __shared__ int   vf[NPTS];

    const int tid = threadIdx.x;
    const int ch  = tid & 63;
    const int wv  = tid >> 6;
    const int base = blockIdx.x * NPTS;
    const int npts = min(NPTS, (int)(N - base));
    if (npts <= 0) return;

    for (int i = tid; i < npts * CIN; i += 256) sf[0][i] = feats[base * CIN + i];
    for (int i = tid; i < npts * 4; i += 256) ((int*)sc)[i] = coors[base * 4 + i];
    __syncthreads();

    for (int off = 0; off < 27; ++off) {
        const int kz = off / 9, ky = (off / 3) % 3, kx = off % 3;
        if (tid < npts) {
            const int p  = tid;
            const int nz = sc[p][1] + 1 - kz;
            const int ny = sc[p][2] + 1 - ky;
            const int nx = sc[p][3] + 1 - kx;
            const int m  = nz | ny | nx;
            const int oz = nz >> 1, oy = ny >> 1, ox = nx >> 1;
            const bool v = ((m & 0x80000001) == 0) &&
                           (oz < OUTD) && (oy < OUTD) && (ox < OUTD);
            vf[p] = v ? (((sc[p][0] * OUTD + oz) * OUTD + oy) * OUTD + ox) : -1;
        }
        const float* wp = Wt + off * (CIN * COUT) + ch;
        float w[CIN];
        #pragma unroll
        for (int c = 0; c < CIN; ++c) w[c] = wp[c * COUT];
        __syncthreads();
        for (int p = wv; p < npts; p += 4) {
            const int f = vf[p];
            if (f >= 0) {
                float s = 0.f;
                #pragma unroll
                for (int c = 0; c < CIN; ++c) s += sf[p][c] * w[c];
                atomicAdd(&out[(size_t)f * COUT + ch], s);
            }
        }
        __syncthreads();
    }
}

extern "C" void kernel_launch(void* const* d_in, const int* in_sizes, int n_in,
                              void* d_out, int out_size, void* d_ws, size_t ws_size,
                              hipStream_t stream) {
    const float* feats = (const float*)d_in[0];
    const float* Wt    = (const float*)d_in[1];
    const int*   coors = (const int*)d_in[2];
    float*       out   = (float*)d_out;

    const int N  = in_sizes[0] / CIN;
    const int B  = out_size / (OUTD * OUTD * OUTD * COUT);
    const int nT = B * NTILE * NTILE * NTILE;

    const size_t histO   = 0;
    const size_t prefO   = histO + nT;
    const size_t cursO   = prefO + nT + 1;
    size_t       pairO   = cursO + nT;
    pairO = (pairO + 3) & ~(size_t)3;                    // 16B align
    const size_t pairsN  = (size_t)N * 8;
    size_t       wO      = pairO + pairsN;
    wO = (wO + 3) & ~(size_t)3;
    const size_t needInt = wO + (27 * CIN * COUT + 1) / 2;  // bf16 W in int units
    const size_t need    = needInt * sizeof(int);

    if (ws_size >= need) {
        int*    wsi    = (int*)d_ws;
        int*    hist   = wsi + histO;
        int*    prefix = wsi + prefO;
        int*    cursor = wsi + cursO;
        int*    pairs  = wsi + pairO;
        ushort* wsW    = (ushort*)(wsi + wO);

        hipMemsetAsync(hist, 0, nT * sizeof(int), stream);
        conv_w_bf16<<<27, 256, 0, stream>>>(Wt, wsW);
        rulebook_count<<<(N + 255) / 256, 256, 0, stream>>>((const int4*)coors, hist, N);
        prefix_scan<<<1, 256, 0, stream>>>(hist, prefix, cursor, nT);
        rulebook_fill<<<(N + 255) / 256, 256, 0, stream>>>((const int4*)coors, cursor, pairs, N);
        gather_tile<<<nT, 256, 0, stream>>>(feats, wsW, pairs, prefix, out);
    } else {
        hipMemsetAsync(d_out, 0, (size_t)out_size * sizeof(float), stream);
        spconv_scatter<<<(N + NPTS - 1) / NPTS, 256, 0, stream>>>(feats, Wt, coors, out, N);
    }
}

// Round 6
// 197.333 us; speedup vs baseline: 1.1710x; 1.1710x over previous
//
#include <hip/hip_runtime.h>

// Sparse 3D conv (K=3, stride=2, pad=1), dense output, rulebook + persistent gather.
// Inputs: features [N,32] f32, W [3,3,3,32,64] f32, coors [N,4] i32 (b,z,y,x).
// Output: [B,64,64,64,64] f32 flat. Exactly-once writes, no output memset.
// ws: [ hist nT | prefix nT+1 | cursor nT | pad | pairs N*8 | W_bf16 27*64*32 ]

#define CIN   32
#define COUT  64
#define OUTD  64
#define TILE  4
#define NTILE 16          // OUTD/TILE
#define CAP2  512         // LDS pair-list chunk
#define NPTS  128
#define NBLK  2048        // persistent gather grid

// Valid (k, o) options along one axis: o = (p+1-k)/2, parity-matched, 0<=o<64.
__device__ __forceinline__ int axis_opts(int p, int* k, int* o) {
    int cnt = 0;
    const int kp = (p + 1) & 1;          // smallest parity-matching k
    const int o0 = (p + 1 - kp) >> 1;    // >= 0 always
    if (o0 < OUTD) { k[cnt] = kp; o[cnt] = o0; ++cnt; }
    if (kp == 0) {                       // k=2 shares parity with k=0
        const int o1 = o0 - 1;
        if (o1 >= 0) { k[cnt] = 2; o[cnt] = o1; ++cnt; }
    }
    return cnt;
}

// ---------- W transpose+quantize + hist zero ----------
__global__ void conv_w_prep(const float* __restrict__ W, ushort* __restrict__ wsW,
                            int* __restrict__ hist, int nT)
{
    const int k = blockIdx.x;            // 27 blocks
    for (int i = k * 256 + threadIdx.x; i < nT; i += 27 * 256) hist[i] = 0;
    for (int i = threadIdx.x; i < CIN * COUT; i += 256) {
        const int c = i >> 6, ch = i & 63;
        const unsigned u = __float_as_uint(W[k * CIN * COUT + i]);
        const unsigned r = (u + 0x7fffu + ((u >> 16) & 1u)) >> 16;   // RNE
        wsW[(k << 11) + (ch << 5) + c] = (ushort)r;
    }
}

// ---------- rulebook pass 1: per-tile pair counts ----------
__global__ void rulebook_count(const int4* __restrict__ coors,
                               int* __restrict__ hist, int N)
{
    const int i = blockIdx.x * 256 + threadIdx.x;
    if (i >= N) return;
    const int4 c = coors[i];             // (b, z, y, x)
    int kz[2], oz[2], ky[2], oy[2], kx[2], ox[2];
    const int nz = axis_opts(c.y, kz, oz);
    const int ny = axis_opts(c.z, ky, oy);
    const int nx = axis_opts(c.w, kx, ox);
    for (int az = 0; az < nz; ++az)
        for (int ay = 0; ay < ny; ++ay)
            for (int ax = 0; ax < nx; ++ax) {
                const int tile = ((c.x * NTILE + (oz[az] >> 2)) * NTILE +
                                  (oy[ay] >> 2)) * NTILE + (ox[ax] >> 2);
                atomicAdd(&hist[tile], 1);
            }
}

// ---------- rulebook pass 2: prefix scan over nT tiles (one block) ----------
__global__ void prefix_scan(const int* __restrict__ hist, int* __restrict__ prefix,
                            int* __restrict__ cursor, int nT)
{
    __shared__ int part[256];
    const int t = threadIdx.x;
    const int chunk = nT >> 8;           // nT is a multiple of 256
    int s = 0;
    for (int i = 0; i < chunk; ++i) s += hist[t * chunk + i];
    part[t] = s;
    __syncthreads();
    if (t == 0) { int r = 0; for (int i = 0; i < 256; ++i) { int v = part[i]; part[i] = r; r += v; } }
    __syncthreads();
    int run = part[t];
    for (int i = 0; i < chunk; ++i) {
        const int idx = t * chunk + i;
        prefix[idx] = run; cursor[idx] = run; run += hist[idx];
    }
    if (t == 255) prefix[nT] = run;
}

// ---------- rulebook pass 3: scatter packed pairs sorted by tile ----------
__global__ void rulebook_fill(const int4* __restrict__ coors,
                              int* __restrict__ cursor, int* __restrict__ pairs, int N)
{
    const int i = blockIdx.x * 256 + threadIdx.x;
    if (i >= N) return;
    const int4 c = coors[i];
    int kz[2], oz[2], ky[2], oy[2], kx[2], ox[2];
    const int nz = axis_opts(c.y, kz, oz);
    const int ny = axis_opts(c.z, ky, oy);
    const int nx = axis_opts(c.w, kx, ox);
    for (int az = 0; az < nz; ++az)
        for (int ay = 0; ay < ny; ++ay)
            for (int ax = 0; ax < nx; ++ax) {
                const int tile = ((c.x * NTILE + (oz[az] >> 2)) * NTILE +
                                  (oy[ay] >> 2)) * NTILE + (ox[ax] >> 2);
                const int kidx = (kz[az] * 3 + ky[ay]) * 3 + kx[ax];
                const int vox  = ((oz[az] & 3) * TILE + (oy[ay] & 3)) * TILE + (ox[ax] & 3);
                const int pos  = atomicAdd(&cursor[tile], 1);
                pairs[pos] = (i << 11) | (kidx << 6) | vox;
            }
}

// ---------- persistent gather: each block grid-strides over tiles ----------
__global__ __launch_bounds__(256) void gather_tiles(
    const float* __restrict__ feats, const ushort* __restrict__ wsW,
    const int* __restrict__ pairs, const int* __restrict__ prefix,
    float* __restrict__ out, int nT, int gridN)
{
    __shared__ float acc[TILE * TILE * TILE * COUT];   // 16 KB
    __shared__ int   list[CAP2];                        // 2 KB

    const int tid = threadIdx.x;
    const int wv = tid >> 6, ch = tid & 63;

    for (int i = tid; i < TILE * TILE * TILE * COUT; i += 256) acc[i] = 0.f;

    for (int tile = blockIdx.x; tile < nT; tile += gridN) {
        int t = tile;
        const int ox0 = (t & 15) * TILE; t >>= 4;
        const int oy0 = (t & 15) * TILE; t >>= 4;
        const int oz0 = (t & 15) * TILE; t >>= 4;
        const int b   = t;

        const int start = prefix[tile], end = prefix[tile + 1];

        for (int base = start; base < end; base += CAP2) {
            const int m = min(CAP2, end - base);
            __syncthreads();   // acc zeroing / list reuse visible to all
            for (int i = tid; i < m; i += 256) list[i] = pairs[base + i];
            __syncthreads();

            #pragma unroll 2
            for (int i = wv; i < m; i += 4) {
                const int e = list[i];
                const int vox = e & 63, k = (e >> 6) & 31;
                const int j = __builtin_amdgcn_readfirstlane(e >> 11);   // wave-uniform
                const float4* fp = (const float4*)(feats + (size_t)j * CIN);
                const uint4*  wp = (const uint4*)(wsW + (k << 11) + (ch << 5));
                float4 f[8];
                #pragma unroll
                for (int q = 0; q < 8; ++q) f[q] = fp[q];
                uint4 w4[4];
                #pragma unroll
                for (int q = 0; q < 4; ++q) w4[q] = wp[q];
                float s = 0.f;
                #pragma unroll
                for (int q = 0; q < 4; ++q) {
                    const uint4 wq = w4[q];
                    const float4 fa = f[2 * q], fb = f[2 * q + 1];
                    s += fa.x * __uint_as_float(wq.x << 16);
                    s += fa.y * __uint_as_float(wq.x & 0xffff0000u);
                    s += fa.z * __uint_as_float(wq.y << 16);
                    s += fa.w * __uint_as_float(wq.y & 0xffff0000u);
                    s += fb.x * __uint_as_float(wq.z << 16);
                    s += fb.y * __uint_as_float(wq.z & 0xffff0000u);
                    s += fb.z * __uint_as_float(wq.w << 16);
                    s += fb.w * __uint_as_float(wq.w & 0xffff0000u);
                }
                unsafeAtomicAdd(&acc[vox * COUT + ch], s);   // ds_add_f32 guaranteed
            }
        }
        __syncthreads();   // all pair accumulation done

        // Write + re-zero: each thread owns its acc words; stores drain async.
        #pragma unroll
        for (int it = 0; it < 4; ++it) {
            const int i = (it * 256 + tid) * 4;
            float4 v = *(float4*)(acc + i);
            *(float4*)(acc + i) = make_float4(0.f, 0.f, 0.f, 0.f);
            const int row = i >> 8;
            const int vz = row >> 2, vy = row & 3;
            const int inrow = i & 255;
            const size_t g = ((((size_t)b * OUTD + (oz0 + vz)) * OUTD + (oy0 + vy)) * OUTD + ox0) * COUT + inrow;
            *(float4*)(out + g) = v;
        }
        // next tile's first __syncthreads orders re-zero before new atomics
    }
}

// ---------- fallback (ws too small): round-1 scatter ----------
__global__ __launch_bounds__(256, 4) void spconv_scatter(
    const float* __restrict__ feats, const float* __restrict__ Wt,
    const int* __restrict__ coors, float* __restrict__ out, int N)
{
    __shared__ float sf[NPTS][CIN];
    __shared__ int   sc[NPTS][4];
    __shared__ int   vf[NPTS];

    const int tid = threadIdx.x;
    const int ch  = tid & 63;
    const int wv  = tid >> 6;
    const int base = blockIdx.x * NPTS;
    const int npts = min(NPTS, (int)(N - base));
    if (npts <= 0) return;

    for (int i = tid; i < npts * CIN; i += 256) sf[0][i] = feats[base * CIN + i];
    for (int i = tid; i < npts * 4; i += 256) ((int*)sc)[i] = coors[base * 4 + i];
    __syncthreads();

    for (int off = 0; off < 27; ++off) {
        const int kz = off / 9, ky = (off / 3) % 3, kx = off % 3;
        if (tid < npts) {
            const int p  = tid;
            const int nz = sc[p][1] + 1 - kz;
            const int ny = sc[p][2] + 1 - ky;
            const int nx = sc[p][3] + 1 - kx;
            const int m  = nz | ny | nx;
            const int oz = nz >> 1, oy = ny >> 1, ox = nx >> 1;
            const bool v = ((m & 0x80000001) == 0) &&
                           (oz < OUTD) && (oy < OUTD) && (ox < OUTD);
            vf[p] = v ? (((sc[p][0] * OUTD + oz) * OUTD + oy) * OUTD + ox) : -1;
        }
        const float* wp = Wt + off * (CIN * COUT) + ch;
        float w[CIN];
        #pragma unroll
        for (int c = 0; c < CIN; ++c) w[c] = wp[c * COUT];
        __syncthreads();
        for (int p = wv; p < npts; p += 4) {
            const int f = vf[p];
            if (f >= 0) {
                float s = 0.f;
                #pragma unroll
                for (int c = 0; c < CIN; ++c) s += sf[p][c] * w[c];
                atomicAdd(&out[(size_t)f * COUT + ch], s);
            }
        }
        __syncthreads();
    }
}

extern "C" void kernel_launch(void* const* d_in, const int* in_sizes, int n_in,
                              void* d_out, int out_size, void* d_ws, size_t ws_size,
                              hipStream_t stream) {
    const float* feats = (const float*)d_in[0];
    const float* Wt    = (const float*)d_in[1];
    const int*   coors = (const int*)d_in[2];
    float*       out   = (float*)d_out;

    const int N  = in_sizes[0] / CIN;
    const int B  = out_size / (OUTD * OUTD * OUTD * COUT);
    const int nT = B * NTILE * NTILE * NTILE;

    const size_t histO   = 0;
    const size_t prefO   = histO + nT;
    const size_t cursO   = prefO + nT + 1;
    size_t       pairO   = cursO + nT;
    pairO = (pairO + 3) & ~(size_t)3;                    // 16B align
    const size_t pairsN  = (size_t)N * 8;
    size_t       wO      = pairO + pairsN;
    wO = (wO + 3) & ~(size_t)3;
    const size_t needInt = wO + (27 * CIN * COUT + 1) / 2;  // bf16 W in int units
    const size_t need    = needInt * sizeof(int);

    if (ws_size >= need) {
        int*    wsi    = (int*)d_ws;
        int*    hist   = wsi + histO;
        int*    prefix = wsi + prefO;
        int*    cursor = wsi + cursO;
        int*    pairs  = wsi + pairO;
        ushort* wsW    = (ushort*)(wsi + wO);

        conv_w_prep<<<27, 256, 0, stream>>>(Wt, wsW, hist, nT);
        rulebook_count<<<(N + 255) / 256, 256, 0, stream>>>((const int4*)coors, hist, N);
        prefix_scan<<<1, 256, 0, stream>>>(hist, prefix, cursor, nT);
        rulebook_fill<<<(N + 255) / 256, 256, 0, stream>>>((const int4*)coors, cursor, pairs, N);
        const int NB = (nT < NBLK) ? nT : NBLK;
        gather_tiles<<<NB, 256, 0, stream>>>(feats, wsW, pairs, prefix, out, nT, NB);
    } else {
        hipMemsetAsync(d_out, 0, (size_t)out_size * sizeof(float), stream);
        spconv_scatter<<<(N + NPTS - 1) / NPTS, 256, 0, stream>>>(feats, Wt, coors, out, N);
    }
}

// Round 7
// 133.473 us; speedup vs baseline: 1.7312x; 1.4784x over previous
//
#include <hip/hip_runtime.h>

// Sparse 3D conv (K=3, stride=2, pad=1), dense output, direct per-point scatter.
// Inputs: features [N,32] f32, W [3,3,3,32,64] f32, coors [N,4] i32 (b,z,y,x).
// Output: [B,64,64,64,64] f32 flat (memset to 0, then posted atomic adds).
// ws: [ W_bf16 27*64*32 ushort ]  (~108 KB)

#define CIN   32
#define COUT  64
#define OUTD  64
#define NBLK  2048
#define NPTS  128

// Valid (k, o) options along one axis: o = (p+1-k)/2, parity-matched, 0<=o<64.
__device__ __forceinline__ int axis_opts(int p, int* k, int* o) {
    int cnt = 0;
    const int kp = (p + 1) & 1;          // smallest parity-matching k
    const int o0 = (p + 1 - kp) >> 1;    // >= 0 always
    if (o0 < OUTD) { k[cnt] = kp; o[cnt] = o0; ++cnt; }
    if (kp == 0) {                       // k=2 shares parity with k=0
        const int o1 = o0 - 1;
        if (o1 >= 0) { k[cnt] = 2; o[cnt] = o1; ++cnt; }
    }
    return cnt;
}

// ---------- W transpose+quantize: [27][32][64] f32 -> [27][64][32] bf16 ----------
__global__ void conv_w_bf16(const float* __restrict__ W, ushort* __restrict__ wsW)
{
    const int k = blockIdx.x;            // 27 blocks
    for (int i = threadIdx.x; i < CIN * COUT; i += 256) {
        const int c = i >> 6, ch = i & 63;
        const unsigned u = __float_as_uint(W[k * CIN * COUT + i]);
        const unsigned r = (u + 0x7fffu + ((u >> 16) & 1u)) >> 16;   // RNE
        wsW[(k << 11) + (ch << 5) + c] = (ushort)r;
    }
}

// ---------- scatter: one wave per point, posted global atomics ----------
__global__ __launch_bounds__(256) void scatter2(
    const float* __restrict__ feats, const ushort* __restrict__ wsW,
    const int4* __restrict__ coors, float* __restrict__ out,
    int N, int totWaves)
{
    const int ch = threadIdx.x & 63;
    const int wv = __builtin_amdgcn_readfirstlane(threadIdx.x >> 6);
    const int gwave = blockIdx.x * 4 + wv;

    for (int i = gwave; i < N; i += totWaves) {
        const int4 c = coors[i];                         // wave-uniform
        const float4* fp = (const float4*)(feats + (size_t)i * CIN);
        float4 f[8];
        #pragma unroll
        for (int q = 0; q < 8; ++q) f[q] = fp[q];        // broadcast row

        int kz[2], oz[2], ky[2], oy[2], kx[2], ox[2];
        const int nz = axis_opts(c.y, kz, oz);
        const int ny = axis_opts(c.z, ky, oy);
        const int nx = axis_opts(c.w, kx, ox);

        for (int az = 0; az < nz; ++az)
        for (int ay = 0; ay < ny; ++ay)
        for (int ax = 0; ax < nx; ++ax) {
            const int kidx = (kz[az] * 3 + ky[ay]) * 3 + kx[ax];
            const uint4* wp = (const uint4*)(wsW + (kidx << 11) + (ch << 5));
            uint4 w4[4];
            #pragma unroll
            for (int q = 0; q < 4; ++q) w4[q] = wp[q];   // 64B/lane, coalesced, L1-hot
            float s0 = 0.f, s1 = 0.f;                    // two chains: halve dep latency
            #pragma unroll
            for (int q = 0; q < 4; ++q) {
                const uint4 wq = w4[q];
                const float4 fa = f[2 * q], fb = f[2 * q + 1];
                s0 += fa.x * __uint_as_float(wq.x << 16);
                s1 += fa.y * __uint_as_float(wq.x & 0xffff0000u);
                s0 += fa.z * __uint_as_float(wq.y << 16);
                s1 += fa.w * __uint_as_float(wq.y & 0xffff0000u);
                s0 += fb.x * __uint_as_float(wq.z << 16);
                s1 += fb.y * __uint_as_float(wq.z & 0xffff0000u);
                s0 += fb.z * __uint_as_float(wq.w << 16);
                s1 += fb.w * __uint_as_float(wq.w & 0xffff0000u);
            }
            const size_t flat = (((size_t)c.x * OUTD + oz[az]) * OUTD + oy[ay]) * OUTD + ox[ax];
            unsafeAtomicAdd(out + flat * COUT + ch, s0 + s1);   // posted, no return
        }
    }
}

// ---------- fallback (ws too small for even W): round-1 scatter ----------
__global__ __launch_bounds__(256, 4) void spconv_scatter(
    const float* __restrict__ feats, const float* __restrict__ Wt,
    const int* __restrict__ coors, float* __restrict__ out, int N)
{
    __shared__ float sf[NPTS][CIN];
    __shared__ int   sc[NPTS][4];
    __shared__ int   vf[NPTS];

    const int tid = threadIdx.x;
    const int ch  = tid & 63;
    const int wv  = tid >> 6;
    const int base = blockIdx.x * NPTS;
    const int npts = min(NPTS, (int)(N - base));
    if (npts <= 0) return;

    for (int i = tid; i < npts * CIN; i += 256) sf[0][i] = feats[base * CIN + i];
    for (int i = tid; i < npts * 4; i += 256) ((int*)sc)[i] = coors[base * 4 + i];
    __syncthreads();

    for (int off = 0; off < 27; ++off) {
        const int kz = off / 9, ky = (off / 3) % 3, kx = off % 3;
        if (tid < npts) {
            const int p  = tid;
            const int nz = sc[p][1] + 1 - kz;
            const int ny = sc[p][2] + 1 - ky;
            const int nx = sc[p][3] + 1 - kx;
            const int m  = nz | ny | nx;
            const int oz = nz >> 1, oy = ny >> 1, ox = nx >> 1;
            const bool v = ((m & 0x80000001) == 0) &&
                           (oz < OUTD) && (oy < OUTD) && (ox < OUTD);
            vf[p] = v ? (((sc[p][0] * OUTD + oz) * OUTD + oy) * OUTD + ox) : -1;
        }
        const float* wp = Wt + off * (CIN * COUT) + ch;
        float w[CIN];
        #pragma unroll
        for (int c = 0; c < CIN; ++c) w[c] = wp[c * COUT];
        __syncthreads();
        for (int p = wv; p < npts; p += 4) {
            const int f = vf[p];
            if (f >= 0) {
                float s = 0.f;
                #pragma unroll
                for (int c = 0; c < CIN; ++c) s += sf[p][c] * w[c];
                atomicAdd(&out[(size_t)f * COUT + ch], s);
            }
        }
        __syncthreads();
    }
}

extern "C" void kernel_launch(void* const* d_in, const int* in_sizes, int n_in,
                              void* d_out, int out_size, void* d_ws, size_t ws_size,
                              hipStream_t stream) {
    const float* feats = (const float*)d_in[0];
    const float* Wt    = (const float*)d_in[1];
    const int*   coors = (const int*)d_in[2];
    float*       out   = (float*)d_out;

    const int N = in_sizes[0] / CIN;

    hipMemsetAsync(d_out, 0, (size_t)out_size * sizeof(float), stream);

    const size_t need = 27 * CIN * COUT * sizeof(ushort);
    if (ws_size >= need) {
        ushort* wsW = (ushort*)d_ws;
        conv_w_bf16<<<27, 256, 0, stream>>>(Wt, wsW);
        const int NB = NBLK;
        scatter2<<<NB, 256, 0, stream>>>(feats, wsW, (const int4*)coors, out, N, NB * 4);
    } else {
        spconv_scatter<<<(N + NPTS - 1) / NPTS, 256, 0, stream>>>(feats, Wt, coors, out, N);
    }
}